// Round 12
// baseline (282.667 us; speedup 1.0000x reference)
//
#include <hip/hip_runtime.h>
#include <hip/hip_bf16.h>
#include <stdint.h>

#define B 2
#define L 2048
#define D 1024
#define H 16
#define HD 64
#define NT (L / 64)          // 32 k-tiles of 64
#define NQT2 (L / 256)       // 8 q-tiles of 256
#define INVALID_CID 0x40000000
#define BHLHD ((size_t)B * H * L * HD)

typedef __hip_bfloat16 bf16;
typedef __attribute__((ext_vector_type(8))) short short8;
typedef __attribute__((ext_vector_type(4))) float floatx4;
typedef __attribute__((ext_vector_type(4))) unsigned int uint4v;

static __device__ __forceinline__ short f2bf(float f) {
    bf16 h = __float2bfloat16(f);
    return *reinterpret_cast<short*>(&h);
}

// async global->LDS, 16B per lane; lptr must be wave-uniform (HW adds lane*16)
static __device__ __forceinline__ void async_copy16(const void* g, void* l) {
    __builtin_amdgcn_global_load_lds((__attribute__((address_space(1))) void*)g,
                                     (__attribute__((address_space(3))) void*)l,
                                     16, 0, 0);
}

// ---------------------------------------------------------------- chain info
__global__ void chain_kernel(const int* __restrict__ lens,
                             float* __restrict__ pos, int* __restrict__ cid,
                             int4* __restrict__ tinfo)
{
    __shared__ int csum[L];
    __shared__ int cids[L];
    __shared__ int part[256];
    int b = blockIdx.x;
    int t = threadIdx.x;

    int loc[8];
    int s = 0;
    #pragma unroll
    for (int j = 0; j < 8; ++j) { s += lens[b * L + t * 8 + j]; loc[j] = s; }
    part[t] = s;
    __syncthreads();
    if (t == 0) {
        int acc = 0;
        for (int i = 0; i < 256; ++i) { int v = part[i]; part[i] = acc; acc += v; }
    }
    __syncthreads();
    int base = part[t];
    #pragma unroll
    for (int j = 0; j < 8; ++j) csum[t * 8 + j] = base + loc[j];
    __syncthreads();

    int total = csum[L - 1];
    for (int p = t; p < L; p += 256) {
        int cv;
        if (p < total) {
            int lo = 0, hi = L;
            while (lo < hi) {
                int mid = (lo + hi) >> 1;
                if (csum[mid] <= p) lo = mid + 1; else hi = mid;
            }
            int prev = (lo > 0) ? csum[lo - 1] : 0;
            pos[b * L + p] = (float)(p - prev);
            cv = lo;
        } else {
            pos[b * L + p] = 0.f;
            cv = INVALID_CID;
        }
        cids[p] = cv;
        cid[b * L + p] = cv;
    }
    __syncthreads();
    if (t < NT) {
        int mn = 0x7fffffff, mx = -1, any = 0, all = 1;
        for (int j = 0; j < 64; ++j) {
            int cv = cids[t * 64 + j];
            if (cv != INVALID_CID) { any = 1; mn = min(mn, cv); mx = max(mx, cv); }
            else all = 0;
        }
        tinfo[b * NT + t] = make_int4(mn, mx, any | (all << 1), 0);
    }
}

// ---------------------------------------------------------------- prep: fused casts + rope table
// blocks 0..11263: bf16 casts (x:4096 | Wi:3072 | We:3072 | Wo:1024, 1024 floats/blk)
// blocks 11264..11775: rope table tab[bl][j] = (cos,sin)(pos[bl]*base^(-j/32))
__global__ void prep_kernel(const float* __restrict__ x,  const float* __restrict__ Wi,
                            const float* __restrict__ We, const float* __restrict__ Wo,
                            bf16* __restrict__ xb, bf16* __restrict__ Wib,
                            bf16* __restrict__ Web, bf16* __restrict__ Wob,
                            const float* __restrict__ pos, float2* __restrict__ tab)
{
    int bid = blockIdx.x;
    if (bid < 11264) {
        const float* src; bf16* dst; int base;
        if      (bid < 4096)  { src = x;  dst = xb;  base = bid; }
        else if (bid < 7168)  { src = Wi; dst = Wib; base = bid - 4096; }
        else if (bid < 10240) { src = We; dst = Web; base = bid - 7168; }
        else                  { src = Wo; dst = Wob; base = bid - 10240; }
        int i = (base * 256 + threadIdx.x) * 4;
        float4 v = *(const float4*)(src + i);
        dst[i + 0] = __float2bfloat16(v.x);
        dst[i + 1] = __float2bfloat16(v.y);
        dst[i + 2] = __float2bfloat16(v.z);
        dst[i + 3] = __float2bfloat16(v.w);
    } else {
        int idx = (bid - 11264) * 256 + threadIdx.x;   // over B*L*32
        int j = idx & 31, l = idx >> 5;
        float invf = exp2f(-(float)j * (13.287712379549449f / 32.f));
        float ang = pos[l] * invf;
        tab[idx] = make_float2(cosf(ang), sinf(ang));
    }
}

// ---------------------------------------------------------------- QKV GEMM + RoPE + scatter (fused)
// 2-phase pipelined K-loop (verified r10): double-buffered LDS, STAGE(t+1) before compute(t),
// one vmcnt-drain barrier per K-step. Epilogue: bias + RoPE + scatter; V via LDS transpose.
__global__ __launch_bounds__(256, 4) void gemm_qkv(
    const bf16* __restrict__ A, const bf16* __restrict__ Bw,
    const float* __restrict__ bi, const float* __restrict__ be,
    const float2* __restrict__ tab,
    bf16* __restrict__ Qo, bf16* __restrict__ Ko, bf16* __restrict__ Vto)
{
    __shared__ short Smem[4 * 128 * 32];   // [buf][A|B][128][32] = 32 KB

    int tid = threadIdx.x;
    int wave = tid >> 6, lane = tid & 63;
    int i15 = lane & 15, q8 = lane >> 4;
    int wm = wave & 1, wn = wave >> 1;
    int m0 = blockIdx.y * 128, n0 = blockIdx.x * 128;
    const int K = D;

    floatx4 acc[4][4];
    #pragma unroll
    for (int mt = 0; mt < 4; ++mt)
        #pragma unroll
        for (int nt = 0; nt < 4; ++nt) acc[mt][nt] = (floatx4){0.f, 0.f, 0.f, 0.f};

    const short* gA = (const short*)A  + (size_t)(m0 + wave * 32 + (lane >> 2)) * K + (lane & 3) * 8;
    const short* gB = (const short*)Bw + (size_t)(n0 + wave * 32 + (lane >> 2)) * K + (lane & 3) * 8;

    auto stage = [&](int bufp, int kt) {
        short* lA = Smem + bufp * 8192 + wave * 1024;
        short* lB = lA + 4096;
        async_copy16(gA + kt,          lA);
        async_copy16(gA + 16 * K + kt, lA + 512);
        async_copy16(gB + kt,          lB);
        async_copy16(gB + 16 * K + kt, lB + 512);
    };

    stage(0, 0);
    __syncthreads();   // drain prologue stage

    int cur = 0;
    for (int kt = 0; kt < K; kt += 32) {
        if (kt + 32 < K) stage(cur ^ 1, kt + 32);   // in flight during this tile's compute

        const short* As = Smem + cur * 8192;
        const short* Bs = As + 4096;
        short8 af[4], bfr[4];
        #pragma unroll
        for (int mt = 0; mt < 4; ++mt)
            af[mt] = *(const short8*)&As[(wm * 64 + mt * 16 + i15) * 32 + q8 * 8];
        #pragma unroll
        for (int nt = 0; nt < 4; ++nt)
            bfr[nt] = *(const short8*)&Bs[(wn * 64 + nt * 16 + i15) * 32 + q8 * 8];
        #pragma unroll
        for (int mt = 0; mt < 4; ++mt)
            #pragma unroll
            for (int nt = 0; nt < 4; ++nt)
                acc[mt][nt] = __builtin_amdgcn_mfma_f32_16x16x32_bf16(af[mt], bfr[nt], acc[mt][nt], 0, 0, 0);

        __syncthreads();   // drains the in-flight stage; releases cur for next overwrite
        cur ^= 1;
    }

    // ---- epilogue ----
    int nb = n0 + wn * 64;               // wave's first col; 64 cols = one (seg, head)
    int segw = nb >> 10;                 // 0 Qi, 1 Ki, 2 Vi, 3 Qe, 4 Ke, 5 Ve
    int br = (segw >= 3);
    int st = segw - 3 * br;              // 0 Q, 1 K, 2 V
    int h = (nb >> 6) & (H - 1);
    int b = m0 >> 11;                    // m0 / L
    int lb = (m0 & (L - 1)) + wm * 64;   // wave's first l

    float bv[4];
    #pragma unroll
    for (int nt = 0; nt < 4; ++nt) {
        int n = nb + nt * 16 + i15;
        bv[nt] = (n < 3 * D) ? bi[n] : be[n - 3 * D];
    }

    if (st != 2) {
        // Q or K: bias + RoPE, write [B,H,L,HD]
        bf16* out = (st == 0 ? Qo : Ko) + (size_t)br * BHLHD;
        const size_t bh = (size_t)(b * H + h) * L;
        float qs = (st == 0) ? 0.18033688011111772f : 1.0f;   // 0.125 * log2(e)
        #pragma unroll
        for (int mt = 0; mt < 4; ++mt) {
            #pragma unroll
            for (int rg = 0; rg < 4; ++rg) {
                int m = m0 + wm * 64 + mt * 16 + q8 * 4 + rg;     // global row
                int l = lb + mt * 16 + q8 * 4 + rg;
                float2 cs0 = tab[(size_t)m * 32 + i15];
                float2 cs1 = tab[(size_t)m * 32 + 16 + i15];
                size_t orow = (bh + l) * HD;
                #pragma unroll
                for (int nt = 0; nt < 4; ++nt) {
                    float x  = acc[mt][nt][rg] + bv[nt];
                    float pr = acc[mt][nt ^ 2][rg] + bv[nt ^ 2];
                    float cc = (nt & 1) ? cs1.x : cs0.x;
                    float ss = (nt & 1) ? cs1.y : cs0.y;
                    float v = qs * (x * cc + ((nt < 2) ? -pr : pr) * ss);
                    out[orow + nt * 16 + i15] = __float2bfloat16(v);
                }
            }
        }
    } else {
        // V: bias, per-wave LDS transpose (reuse staging LDS), write [B,H,HD,L]
        bf16* out = Vto + (size_t)br * BHLHD;
        const size_t bhd = (size_t)(b * H + h) * HD;
        __syncthreads();                      // all waves done reading Smem
        short* vts = Smem + wave * 64 * 20;   // [64 hd][20] shorts, rows 40 B (bank-safe, 8B-aligned)
        #pragma unroll
        for (int mt = 0; mt < 4; ++mt) {
            #pragma unroll
            for (int nt = 0; nt < 4; ++nt) {
                uint2 w;
                w.x = (unsigned)(unsigned short)f2bf(acc[mt][nt][0] + bv[nt]) |
                      ((unsigned)(unsigned short)f2bf(acc[mt][nt][1] + bv[nt]) << 16);
                w.y = (unsigned)(unsigned short)f2bf(acc[mt][nt][2] + bv[nt]) |
                      ((unsigned)(unsigned short)f2bf(acc[mt][nt][3] + bv[nt]) << 16);
                *(uint2*)&vts[(nt * 16 + i15) * 20 + q8 * 4] = w;   // row hd, cols m-local
            }
            // same-wave read back: lane <-> hd row, 16 m-local shorts
            uint2 r0 = *(const uint2*)&vts[lane * 20 + 0];
            uint2 r1 = *(const uint2*)&vts[lane * 20 + 4];
            uint2 r2 = *(const uint2*)&vts[lane * 20 + 8];
            uint2 r3 = *(const uint2*)&vts[lane * 20 + 12];
            size_t ga = (bhd + lane) * L + lb + mt * 16;
            uint4v v0 = (uint4v){r0.x, r0.y, r1.x, r1.y};
            uint4v v1 = (uint4v){r2.x, r2.y, r3.x, r3.y};
            *(uint4v*)&out[ga]     = v0;
            *(uint4v*)&out[ga + 8] = v1;
        }
    }
}

// ---------------------------------------------------------------- GEMM (out-proj, 2-phase pipelined)
__global__ __launch_bounds__(256, 4) void gemm128(
    const bf16* __restrict__ A, const bf16* __restrict__ Bw,
    const float* __restrict__ bias, void* __restrict__ Cout,
    int M, int N, int K, int c_bf16)
{
    __shared__ short Smem[4 * 128 * 32];   // 32 KB double-buffered

    int tid = threadIdx.x;
    int wave = tid >> 6, lane = tid & 63;
    int i15 = lane & 15, q8 = lane >> 4;
    int wm = wave & 1, wn = wave >> 1;
    int m0 = blockIdx.y * 128, n0 = blockIdx.x * 128;

    floatx4 acc[4][4];
    #pragma unroll
    for (int mt = 0; mt < 4; ++mt)
        #pragma unroll
        for (int nt = 0; nt < 4; ++nt) acc[mt][nt] = (floatx4){0.f, 0.f, 0.f, 0.f};

    const short* gA = (const short*)A  + (size_t)(m0 + wave * 32 + (lane >> 2)) * K + (lane & 3) * 8;
    const short* gB = (const short*)Bw + (size_t)(n0 + wave * 32 + (lane >> 2)) * K + (lane & 3) * 8;

    auto stage = [&](int bufp, int kt) {
        short* lA = Smem + bufp * 8192 + wave * 1024;
        short* lB = lA + 4096;
        async_copy16(gA + kt,          lA);
        async_copy16(gA + 16 * K + kt, lA + 512);
        async_copy16(gB + kt,          lB);
        async_copy16(gB + 16 * K + kt, lB + 512);
    };

    stage(0, 0);
    __syncthreads();

    int cur = 0;
    for (int kt = 0; kt < K; kt += 32) {
        if (kt + 32 < K) stage(cur ^ 1, kt + 32);

        const short* As = Smem + cur * 8192;
        const short* Bs = As + 4096;
        short8 af[4], bfr[4];
        #pragma unroll
        for (int mt = 0; mt < 4; ++mt)
            af[mt] = *(const short8*)&As[(wm * 64 + mt * 16 + i15) * 32 + q8 * 8];
        #pragma unroll
        for (int nt = 0; nt < 4; ++nt)
            bfr[nt] = *(const short8*)&Bs[(wn * 64 + nt * 16 + i15) * 32 + q8 * 8];
        #pragma unroll
        for (int mt = 0; mt < 4; ++mt)
            #pragma unroll
            for (int nt = 0; nt < 4; ++nt)
                acc[mt][nt] = __builtin_amdgcn_mfma_f32_16x16x32_bf16(af[mt], bfr[nt], acc[mt][nt], 0, 0, 0);

        __syncthreads();
        cur ^= 1;
    }

    #pragma unroll
    for (int nt = 0; nt < 4; ++nt) {
        int n = n0 + wn * 64 + nt * 16 + i15;
        float bv = bias[n];
        #pragma unroll
        for (int mt = 0; mt < 4; ++mt) {
            #pragma unroll
            for (int rg = 0; rg < 4; ++rg) {
                int m = m0 + wm * 64 + mt * 16 + q8 * 4 + rg;
                float v = acc[mt][nt][rg] + bv;
                if (c_bf16) ((bf16*)Cout)[(size_t)m * N + n] = __float2bfloat16(v);
                else        ((float*)Cout)[(size_t)m * N + n] = v;
            }
        }
    }
}

// ---------------------------------------------------------------- MFMA flash attention v12
// = v11 (QBLK=256, 8 waves, merged branches, sigma-perm K, in-register P) but processing
// TWO k-tiles per barrier window: stage pair -> ONE barrier -> prefetch next pair ->
// compute both tiles. Iterations (and their barrier + vmcnt-drain fixed cost) halve.
// LDS: 2 pair-buffers x 2 slots x (K+V) x [64][72] = 73.7 KB -> 1 block/CU (grid=256=1/CU).
__global__ __launch_bounds__(512, 1) void attn12(
    const bf16* __restrict__ Qg, const bf16* __restrict__ Kgg, const bf16* __restrict__ Vtgg,
    const int* __restrict__ cid, const int4* __restrict__ tinfo,
    bf16* __restrict__ Out)
{
    __shared__ short Ks[2][2][64][72];   // [pairbuf][slot][row][col]
    __shared__ short Vs[2][2][64][72];
    __shared__ int cls0_s[NT], cls1_s[NT];
    __shared__ int list_s[2][NT];
    __shared__ int nlist_s[2];

    int tid = threadIdx.x;
    int wave = tid >> 6, lane = tid & 63;
    int i15 = lane & 15, q8 = lane >> 4;
    int workid = ((blockIdx.x & 7) << 5) | (blockIdx.x >> 3);   // 256 blocks, XCD-chunked
    int qt = workid & (NQT2 - 1);
    int h  = (workid >> 3) & (H - 1);
    int b  = workid >> 7;
    int q0 = qt * 256;
    const size_t bh  = (size_t)(b * H + h) * L;
    const size_t bhd = (size_t)(b * H + h) * HD;

    int cq[2];
    #pragma unroll
    for (int g = 0; g < 2; ++g)
        cq[g] = cid[b * L + q0 + g * 128 + wave * 16 + i15];

    // merge the four 64-q tinfo entries for this 256-q block
    int4 qinf;
    {
        int4 e0 = tinfo[b * NT + 4 * qt];
        int4 e1 = tinfo[b * NT + 4 * qt + 1];
        int4 e2 = tinfo[b * NT + 4 * qt + 2];
        int4 e3 = tinfo[b * NT + 4 * qt + 3];
        qinf.x = min(min(e0.x, e1.x), min(e2.x, e3.x));
        qinf.y = max(max(e0.y, e1.y), max(e2.y, e3.y));
        qinf.z = ((e0.z | e1.z | e2.z | e3.z) & 1) | (e0.z & e1.z & e2.z & e3.z & 2);
    }
    int qall = (qinf.z >> 1) & 1;

    if (tid < NT) {
        int4 ki = tinfo[b * NT + tid];
        int kany = ki.z & 1, kall = (ki.z >> 1) & 1;
        bool disjoint = (ki.x > qinf.y) || (ki.y < qinf.x);
        bool mono = qall && kall && (qinf.x == qinf.y) && (ki.x == ki.y) && (qinf.x == ki.x);
        cls0_s[tid] = (!kany || disjoint) ? 0 : (mono ? 2 : 1);
        cls1_s[tid] = (!kany || mono) ? 0 : ((kall && disjoint) ? 2 : 1);
    }
    __syncthreads();
    if (tid < 2) {
        const int* cls = tid ? cls1_s : cls0_s;
        int n = 0;
        for (int t = 0; t < NT; ++t) {
            int c = cls[t];
            if (c) list_s[tid][n++] = (t * 64) | ((c == 2) << 16);
        }
        nlist_s[tid] = n;
    }
    __syncthreads();

    // staging geometry: 512 threads -> row r = tid>>3, 8-short chunk c8 = (tid&7)*8.
    // K stored at sigma-permuted row sr(r); V at plain row r.
    int r = tid >> 3, c8 = (tid & 7) * 8;
    int sr = ((((r >> 2) & 1) | ((r >> 5) << 1)) << 4) | (((r >> 3) & 3) << 2) | (r & 3);

    floatx4 accO[2][2][4];   // [branch][g][t]
    #pragma unroll
    for (int brq = 0; brq < 2; ++brq)
        #pragma unroll
        for (int g = 0; g < 2; ++g)
            #pragma unroll
            for (int t = 0; t < 4; ++t) accO[brq][g][t] = (floatx4){0.f, 0.f, 0.f, 0.f};
    float lsum[2][2] = {{0.f, 0.f}, {0.f, 0.f}};

    // one k-tile: QK^T (log2 domain) -> mask -> exp2 -> in-register P -> PV accumulate
    auto compute_tile = [&](const short (*Kt)[72], const short (*Vt)[72],
                            int kt, int full, short8 (&qfb)[2][2],
                            floatx4 (&aO)[2][4], float (&ls)[2], int brv) {
        unsigned int dl[2][4], dh[2][4];
        #pragma unroll
        for (int t = 0; t < 4; ++t) {
            short8 b0 = *(const short8*)&Kt[t * 16 + i15][q8 * 8];
            short8 b1 = *(const short8*)&Kt[t * 16 + i15][32 + q8 * 8];

            floatx4 accS[2];
            #pragma unroll
            for (int g = 0; g < 2; ++g) {
                accS[g] = (floatx4){0.f, 0.f, 0.f, 0.f};
                accS[g] = __builtin_amdgcn_mfma_f32_16x16x32_bf16(b0, qfb[g][0], accS[g], 0, 0, 0);
                accS[g] = __builtin_amdgcn_mfma_f32_16x16x32_bf16(b1, qfb[g][1], accS[g], 0, 0, 0);
            }

            if (!full) {
                int4 ck4 = *(const int4*)(cid + b * L + kt + (q8 << 3) + ((t & 1) << 2) + ((t >> 1) << 5));
                int ckr[4] = {ck4.x, ck4.y, ck4.z, ck4.w};
                #pragma unroll
                for (int g = 0; g < 2; ++g)
                    #pragma unroll
                    for (int rg = 0; rg < 4; ++rg) {
                        bool kv = (ckr[rg] != INVALID_CID);
                        bool match = (cq[g] == ckr[rg]);
                        bool ok = kv && (brv ? !match : match);
                        accS[g][rg] = ok ? accS[g][rg] : -1e30f;
                    }
            }

            #pragma unroll
            for (int g = 0; g < 2; ++g) {
                float p0 = __builtin_amdgcn_exp2f(accS[g][0]);
                float p1 = __builtin_amdgcn_exp2f(accS[g][1]);
                float p2 = __builtin_amdgcn_exp2f(accS[g][2]);
                float p3 = __builtin_amdgcn_exp2f(accS[g][3]);
                ls[g] += (p0 + p1) + (p2 + p3);
                dl[g][t] = (unsigned)(unsigned short)f2bf(p0) | ((unsigned)(unsigned short)f2bf(p1) << 16);
                dh[g][t] = (unsigned)(unsigned short)f2bf(p2) | ((unsigned)(unsigned short)f2bf(p3) << 16);
            }
        }

        union { uint4v u; short8 s; } pa0[2], pa1[2];
        #pragma unroll
        for (int g = 0; g < 2; ++g) {
            pa0[g].u = (uint4v){dl[g][0], dh[g][0], dl[g][1], dh[g][1]};
            pa1[g].u = (uint4v){dl[g][2], dh[g][2], dl[g][3], dh[g][3]};
        }

        #pragma unroll
        for (int dt = 0; dt < 4; ++dt) {
            short8 vf0 = *(const short8*)&Vt[dt * 16 + i15][q8 * 8];
            short8 vf1 = *(const short8*)&Vt[dt * 16 + i15][32 + q8 * 8];
            #pragma unroll
            for (int g = 0; g < 2; ++g) {
                aO[g][dt] = __builtin_amdgcn_mfma_f32_16x16x32_bf16(pa0[g].s, vf0, aO[g][dt], 0, 0, 0);
                aO[g][dt] = __builtin_amdgcn_mfma_f32_16x16x32_bf16(pa1[g].s, vf1, aO[g][dt], 0, 0, 0);
            }
        }
    };

    #pragma unroll
    for (int br = 0; br < 2; ++br) {
        const short* Qb    = (const short*)Qg   + (size_t)br * BHLHD;
        const short* Kbase = (const short*)Kgg  + (size_t)br * BHLHD + (bh + r) * HD + c8;
        const short* Vbase = (const short*)Vtgg + (size_t)br * BHLHD + (bhd + r) * L + c8;
        int n = nlist_s[br];

        // Q fragments for this branch (wave's 2 x 16 q rows)
        short8 qf[2][2];
        #pragma unroll
        for (int g = 0; g < 2; ++g) {
            const short* qp = Qb + (bh + q0 + g * 128 + wave * 16 + i15) * HD + q8 * 8;
            qf[g][0] = *(const short8*)(qp);
            qf[g][1] = *(const short8*)(qp + 32);
        }

        // prologue: register-prefetch pair 0
        int e0 = 0, e1 = 0;
        int4 pk0, pv0, pk1, pv1;
        if (n > 0) {
            e0 = list_s[br][0];
            int kt0 = e0 & 0xffff;
            pk0 = *(const int4*)(Kbase + (size_t)kt0 * HD);
            pv0 = *(const int4*)(Vbase + kt0);
        }
        if (n > 1) {
            e1 = list_s[br][1];
            int kt1 = e1 & 0xffff;
            pk1 = *(const int4*)(Kbase + (size_t)kt1 * HD);
            pv1 = *(const int4*)(Vbase + kt1);
        }
        __syncthreads();   // prior phase's reads done before overwriting buffers

        for (int i = 0; i < n; i += 2) {
            int pb = (i >> 1) & 1;
            int kt0 = e0 & 0xffff, f0 = e0 >> 16;
            int kt1 = e1 & 0xffff, f1 = e1 >> 16;
            bool has1 = (i + 1 < n);

            *(int4*)&Ks[pb][0][sr][c8] = pk0;
            *(int4*)&Vs[pb][0][r][c8]  = pv0;
            if (has1) {
                *(int4*)&Ks[pb][1][sr][c8] = pk1;
                *(int4*)&Vs[pb][1][r][c8]  = pv1;
            }
            __syncthreads();

            // register-prefetch next pair (in flight across both tiles' compute)
            if (i + 2 < n) {
                e0 = list_s[br][i + 2];
                int nk = e0 & 0xffff;
                pk0 = *(const int4*)(Kbase + (size_t)nk * HD);
                pv0 = *(const int4*)(Vbase + nk);
            }
            if (i + 3 < n) {
                e1 = list_s[br][i + 3];
                int nk = e1 & 0xffff;
                pk1 = *(const int4*)(Kbase + (size_t)nk * HD);
                pv1 = *(const int4*)(Vbase + nk);
            }

            compute_tile(Ks[pb][0], Vs[pb][0], kt0, f0, qf, accO[br], lsum[br], br);
            if (has1)
                compute_tile(Ks[pb][1], Vs[pb][1], kt1, f1, qf, accO[br], lsum[br], br);
        }
    }

    // row-sum reduce per branch/group, then single bf16 output write
    float inv[2][2][4];
    #pragma unroll
    for (int br = 0; br < 2; ++br)
        #pragma unroll
        for (int g = 0; g < 2; ++g) {
            float ls = lsum[br][g];
            ls += __shfl_xor(ls, 16, 64);
            ls += __shfl_xor(ls, 32, 64);
            #pragma unroll
            for (int rg = 0; rg < 4; ++rg) {
                float lv = __shfl(ls, q8 * 4 + rg, 64);
                inv[br][g][rg] = (lv > 0.f) ? 1.f / lv : 0.f;
            }
        }

    #pragma unroll
    for (int g = 0; g < 2; ++g)
        #pragma unroll
        for (int t = 0; t < 4; ++t)
            #pragma unroll
            for (int rg = 0; rg < 4; ++rg) {
                size_t idx = (size_t)(b * L + q0 + g * 128 + wave * 16 + q8 * 4 + rg) * D + h * HD + t * 16 + i15;
                float o = accO[0][g][t][rg] * inv[0][g][rg] + accO[1][g][t][rg] * inv[1][g][rg];
                Out[idx] = __float2bfloat16(o);
            }
}

// ---------------------------------------------------------------- launch
extern "C" void kernel_launch(void* const* d_in, const int* in_sizes, int n_in,
                              void* d_out, int out_size, void* d_ws, size_t ws_size,
                              hipStream_t stream)
{
    const float* x    = (const float*)d_in[0];
    const int*   mlen = (const int*)  d_in[1];
    const float* Wi   = (const float*)d_in[2];
    const float* bi   = (const float*)d_in[3];
    const float* We   = (const float*)d_in[4];
    const float* be   = (const float*)d_in[5];
    const float* Wo   = (const float*)d_in[6];
    const float* bo   = (const float*)d_in[7];

    char* ws = (char*)d_ws;
    size_t off = 0;
    auto alloc = [&](size_t bytes) {
        void* p = ws + off;
        off += (bytes + 255) & ~(size_t)255;
        return p;
    };
    bf16*  x_b   = (bf16*) alloc((size_t)B * L * D * 2);
    bf16*  Wi_b  = (bf16*) alloc((size_t)3 * D * D * 2);   // adjacent to We_b: combined [6144][1024]
    bf16*  We_b  = (bf16*) alloc((size_t)3 * D * D * 2);
    bf16*  Wo_b  = (bf16*) alloc((size_t)D * D * 2);
    bf16*  q_b   = (bf16*) alloc(2 * BHLHD * 2);           // [branch][B,H,L,HD]
    bf16*  k_b   = (bf16*) alloc(2 * BHLHD * 2);
    bf16*  vt_b  = (bf16*) alloc(2 * BHLHD * 2);           // [branch][B,H,HD,L]
    bf16*  sum_b = (bf16*) alloc((size_t)B * L * D * 2);
    float* pos   = (float*)alloc((size_t)B * L * 4);
    int*   cid   = (int*)  alloc((size_t)B * L * 4);
    int4*  tinfo = (int4*) alloc((size_t)B * NT * 16);
    float2* rtab = (float2*)alloc((size_t)B * L * 32 * 8);
    (void)ws_size; (void)n_in; (void)in_sizes; (void)out_size;

    chain_kernel<<<B, 256, 0, stream>>>(mlen, pos, cid, tinfo);

    // fused casts + rope table (rope depends on chain's pos; casts independent)
    prep_kernel<<<11776, 256, 0, stream>>>(x, Wi, We, Wo, x_b, Wi_b, We_b, Wo_b, pos, rtab);

    // fused QKV GEMM + bias + RoPE + scatter (both branches in one pass)
    dim3 gq(6 * D / 128, B * L / 128);
    gemm_qkv<<<gq, 256, 0, stream>>>(x_b, Wi_b, bi, be, rtab, q_b, k_b, vt_b);

    // both attention branches in one dispatch: 8 waves x 256 q rows, 2 k-tiles per barrier
    attn12<<<B * H * NQT2, 512, 0, stream>>>(q_b, k_b, vt_b, cid, tinfo, sum_b);

    dim3 go(D / 128, B * L / 128);
    gemm128<<<go, 256, 0, stream>>>(sum_b, Wo_b, bo, d_out, B * L, D, D, 0);
}

// Round 13
// 279.657 us; speedup vs baseline: 1.0108x; 1.0108x over previous
//
#include <hip/hip_runtime.h>
#include <hip/hip_bf16.h>
#include <stdint.h>

#define B 2
#define L 2048
#define D 1024
#define H 16
#define HD 64
#define NT (L / 64)          // 32 k-tiles of 64
#define NQT2 (L / 256)       // 8 q-tiles of 256
#define INVALID_CID 0x40000000
#define BHLHD ((size_t)B * H * L * HD)

typedef __hip_bfloat16 bf16;
typedef __attribute__((ext_vector_type(8))) short short8;
typedef __attribute__((ext_vector_type(4))) float floatx4;
typedef __attribute__((ext_vector_type(4))) unsigned int uint4v;

static __device__ __forceinline__ short f2bf(float f) {
    bf16 h = __float2bfloat16(f);
    return *reinterpret_cast<short*>(&h);
}

// async global->LDS, 16B per lane; lptr must be wave-uniform (HW adds lane*16)
static __device__ __forceinline__ void async_copy16(const void* g, void* l) {
    __builtin_amdgcn_global_load_lds((__attribute__((address_space(1))) void*)g,
                                     (__attribute__((address_space(3))) void*)l,
                                     16, 0, 0);
}

// ---------------------------------------------------------------- chain info
// v13: serial 256-iteration t==0 prefix scan replaced by Hillis-Steele parallel scan
// (the serial scan was ~64k dependent-LDS cycles ≈ 20+ us on a 2-block grid).
__global__ void chain_kernel(const int* __restrict__ lens,
                             float* __restrict__ pos, int* __restrict__ cid,
                             int4* __restrict__ tinfo)
{
    __shared__ int csum[L];
    __shared__ int cids[L];
    __shared__ int part[256];
    int b = blockIdx.x;
    int t = threadIdx.x;

    int loc[8];
    int s = 0;
    #pragma unroll
    for (int j = 0; j < 8; ++j) { s += lens[b * L + t * 8 + j]; loc[j] = s; }
    part[t] = s;
    __syncthreads();

    // Hillis-Steele inclusive scan over part[0..255]
    #pragma unroll
    for (int d = 1; d < 256; d <<= 1) {
        int v = (t >= d) ? part[t - d] : 0;
        __syncthreads();
        part[t] += v;
        __syncthreads();
    }
    int base = (t > 0) ? part[t - 1] : 0;   // exclusive prefix
    #pragma unroll
    for (int j = 0; j < 8; ++j) csum[t * 8 + j] = base + loc[j];
    __syncthreads();

    int total = csum[L - 1];
    for (int p = t; p < L; p += 256) {
        int cv;
        if (p < total) {
            int lo = 0, hi = L;
            while (lo < hi) {
                int mid = (lo + hi) >> 1;
                if (csum[mid] <= p) lo = mid + 1; else hi = mid;
            }
            int prev = (lo > 0) ? csum[lo - 1] : 0;
            pos[b * L + p] = (float)(p - prev);
            cv = lo;
        } else {
            pos[b * L + p] = 0.f;
            cv = INVALID_CID;
        }
        cids[p] = cv;
        cid[b * L + p] = cv;
    }
    __syncthreads();
    if (t < NT) {
        int mn = 0x7fffffff, mx = -1, any = 0, all = 1;
        for (int j = 0; j < 64; ++j) {
            int cv = cids[t * 64 + j];
            if (cv != INVALID_CID) { any = 1; mn = min(mn, cv); mx = max(mx, cv); }
            else all = 0;
        }
        tinfo[b * NT + t] = make_int4(mn, mx, any | (all << 1), 0);
    }
}

// ---------------------------------------------------------------- prep: fused casts + rope table
// blocks 0..11263: bf16 casts (x:4096 | Wi:3072 | We:3072 | Wo:1024, 1024 floats/blk)
// blocks 11264..11775: rope table tab[bl][j] = (cos,sin)(pos[bl]*base^(-j/32))
__global__ void prep_kernel(const float* __restrict__ x,  const float* __restrict__ Wi,
                            const float* __restrict__ We, const float* __restrict__ Wo,
                            bf16* __restrict__ xb, bf16* __restrict__ Wib,
                            bf16* __restrict__ Web, bf16* __restrict__ Wob,
                            const float* __restrict__ pos, float2* __restrict__ tab)
{
    int bid = blockIdx.x;
    if (bid < 11264) {
        const float* src; bf16* dst; int base;
        if      (bid < 4096)  { src = x;  dst = xb;  base = bid; }
        else if (bid < 7168)  { src = Wi; dst = Wib; base = bid - 4096; }
        else if (bid < 10240) { src = We; dst = Web; base = bid - 7168; }
        else                  { src = Wo; dst = Wob; base = bid - 10240; }
        int i = (base * 256 + threadIdx.x) * 4;
        float4 v = *(const float4*)(src + i);
        dst[i + 0] = __float2bfloat16(v.x);
        dst[i + 1] = __float2bfloat16(v.y);
        dst[i + 2] = __float2bfloat16(v.z);
        dst[i + 3] = __float2bfloat16(v.w);
    } else {
        int idx = (bid - 11264) * 256 + threadIdx.x;   // over B*L*32
        int j = idx & 31, l = idx >> 5;
        float invf = exp2f(-(float)j * (13.287712379549449f / 32.f));
        float ang = pos[l] * invf;
        tab[idx] = make_float2(cosf(ang), sinf(ang));
    }
}

// ---------------------------------------------------------------- QKV GEMM + RoPE + scatter (fused)
// 2-phase pipelined K-loop (verified r10): double-buffered LDS, STAGE(t+1) before compute(t),
// one vmcnt-drain barrier per K-step. Epilogue: bias + RoPE + scatter; V via LDS transpose.
__global__ __launch_bounds__(256, 4) void gemm_qkv(
    const bf16* __restrict__ A, const bf16* __restrict__ Bw,
    const float* __restrict__ bi, const float* __restrict__ be,
    const float2* __restrict__ tab,
    bf16* __restrict__ Qo, bf16* __restrict__ Ko, bf16* __restrict__ Vto)
{
    __shared__ short Smem[4 * 128 * 32];   // [buf][A|B][128][32] = 32 KB

    int tid = threadIdx.x;
    int wave = tid >> 6, lane = tid & 63;
    int i15 = lane & 15, q8 = lane >> 4;
    int wm = wave & 1, wn = wave >> 1;
    int m0 = blockIdx.y * 128, n0 = blockIdx.x * 128;
    const int K = D;

    floatx4 acc[4][4];
    #pragma unroll
    for (int mt = 0; mt < 4; ++mt)
        #pragma unroll
        for (int nt = 0; nt < 4; ++nt) acc[mt][nt] = (floatx4){0.f, 0.f, 0.f, 0.f};

    const short* gA = (const short*)A  + (size_t)(m0 + wave * 32 + (lane >> 2)) * K + (lane & 3) * 8;
    const short* gB = (const short*)Bw + (size_t)(n0 + wave * 32 + (lane >> 2)) * K + (lane & 3) * 8;

    auto stage = [&](int bufp, int kt) {
        short* lA = Smem + bufp * 8192 + wave * 1024;
        short* lB = lA + 4096;
        async_copy16(gA + kt,          lA);
        async_copy16(gA + 16 * K + kt, lA + 512);
        async_copy16(gB + kt,          lB);
        async_copy16(gB + 16 * K + kt, lB + 512);
    };

    stage(0, 0);
    __syncthreads();   // drain prologue stage

    int cur = 0;
    for (int kt = 0; kt < K; kt += 32) {
        if (kt + 32 < K) stage(cur ^ 1, kt + 32);   // in flight during this tile's compute

        const short* As = Smem + cur * 8192;
        const short* Bs = As + 4096;
        short8 af[4], bfr[4];
        #pragma unroll
        for (int mt = 0; mt < 4; ++mt)
            af[mt] = *(const short8*)&As[(wm * 64 + mt * 16 + i15) * 32 + q8 * 8];
        #pragma unroll
        for (int nt = 0; nt < 4; ++nt)
            bfr[nt] = *(const short8*)&Bs[(wn * 64 + nt * 16 + i15) * 32 + q8 * 8];
        #pragma unroll
        for (int mt = 0; mt < 4; ++mt)
            #pragma unroll
            for (int nt = 0; nt < 4; ++nt)
                acc[mt][nt] = __builtin_amdgcn_mfma_f32_16x16x32_bf16(af[mt], bfr[nt], acc[mt][nt], 0, 0, 0);

        __syncthreads();   // drains the in-flight stage; releases cur for next overwrite
        cur ^= 1;
    }

    // ---- epilogue ----
    int nb = n0 + wn * 64;               // wave's first col; 64 cols = one (seg, head)
    int segw = nb >> 10;                 // 0 Qi, 1 Ki, 2 Vi, 3 Qe, 4 Ke, 5 Ve
    int br = (segw >= 3);
    int st = segw - 3 * br;              // 0 Q, 1 K, 2 V
    int h = (nb >> 6) & (H - 1);
    int b = m0 >> 11;                    // m0 / L
    int lb = (m0 & (L - 1)) + wm * 64;   // wave's first l

    float bv[4];
    #pragma unroll
    for (int nt = 0; nt < 4; ++nt) {
        int n = nb + nt * 16 + i15;
        bv[nt] = (n < 3 * D) ? bi[n] : be[n - 3 * D];
    }

    if (st != 2) {
        // Q or K: bias + RoPE, write [B,H,L,HD]
        bf16* out = (st == 0 ? Qo : Ko) + (size_t)br * BHLHD;
        const size_t bh = (size_t)(b * H + h) * L;
        float qs = (st == 0) ? 0.18033688011111772f : 1.0f;   // 0.125 * log2(e)
        #pragma unroll
        for (int mt = 0; mt < 4; ++mt) {
            #pragma unroll
            for (int rg = 0; rg < 4; ++rg) {
                int m = m0 + wm * 64 + mt * 16 + q8 * 4 + rg;     // global row
                int l = lb + mt * 16 + q8 * 4 + rg;
                float2 cs0 = tab[(size_t)m * 32 + i15];
                float2 cs1 = tab[(size_t)m * 32 + 16 + i15];
                size_t orow = (bh + l) * HD;
                #pragma unroll
                for (int nt = 0; nt < 4; ++nt) {
                    float x  = acc[mt][nt][rg] + bv[nt];
                    float pr = acc[mt][nt ^ 2][rg] + bv[nt ^ 2];
                    float cc = (nt & 1) ? cs1.x : cs0.x;
                    float ss = (nt & 1) ? cs1.y : cs0.y;
                    float v = qs * (x * cc + ((nt < 2) ? -pr : pr) * ss);
                    out[orow + nt * 16 + i15] = __float2bfloat16(v);
                }
            }
        }
    } else {
        // V: bias, per-wave LDS transpose (reuse staging LDS), write [B,H,HD,L]
        bf16* out = Vto + (size_t)br * BHLHD;
        const size_t bhd = (size_t)(b * H + h) * HD;
        __syncthreads();                      // all waves done reading Smem
        short* vts = Smem + wave * 64 * 20;   // [64 hd][20] shorts, rows 40 B (bank-safe, 8B-aligned)
        #pragma unroll
        for (int mt = 0; mt < 4; ++mt) {
            #pragma unroll
            for (int nt = 0; nt < 4; ++nt) {
                uint2 w;
                w.x = (unsigned)(unsigned short)f2bf(acc[mt][nt][0] + bv[nt]) |
                      ((unsigned)(unsigned short)f2bf(acc[mt][nt][1] + bv[nt]) << 16);
                w.y = (unsigned)(unsigned short)f2bf(acc[mt][nt][2] + bv[nt]) |
                      ((unsigned)(unsigned short)f2bf(acc[mt][nt][3] + bv[nt]) << 16);
                *(uint2*)&vts[(nt * 16 + i15) * 20 + q8 * 4] = w;   // row hd, cols m-local
            }
            // same-wave read back: lane <-> hd row, 16 m-local shorts
            uint2 r0 = *(const uint2*)&vts[lane * 20 + 0];
            uint2 r1 = *(const uint2*)&vts[lane * 20 + 4];
            uint2 r2 = *(const uint2*)&vts[lane * 20 + 8];
            uint2 r3 = *(const uint2*)&vts[lane * 20 + 12];
            size_t ga = (bhd + lane) * L + lb + mt * 16;
            uint4v v0 = (uint4v){r0.x, r0.y, r1.x, r1.y};
            uint4v v1 = (uint4v){r2.x, r2.y, r3.x, r3.y};
            *(uint4v*)&out[ga]     = v0;
            *(uint4v*)&out[ga + 8] = v1;
        }
    }
}

// ---------------------------------------------------------------- GEMM (out-proj, 2-phase pipelined)
__global__ __launch_bounds__(256, 4) void gemm128(
    const bf16* __restrict__ A, const bf16* __restrict__ Bw,
    const float* __restrict__ bias, void* __restrict__ Cout,
    int M, int N, int K, int c_bf16)
{
    __shared__ short Smem[4 * 128 * 32];   // 32 KB double-buffered

    int tid = threadIdx.x;
    int wave = tid >> 6, lane = tid & 63;
    int i15 = lane & 15, q8 = lane >> 4;
    int wm = wave & 1, wn = wave >> 1;
    int m0 = blockIdx.y * 128, n0 = blockIdx.x * 128;

    floatx4 acc[4][4];
    #pragma unroll
    for (int mt = 0; mt < 4; ++mt)
        #pragma unroll
        for (int nt = 0; nt < 4; ++nt) acc[mt][nt] = (floatx4){0.f, 0.f, 0.f, 0.f};

    const short* gA = (const short*)A  + (size_t)(m0 + wave * 32 + (lane >> 2)) * K + (lane & 3) * 8;
    const short* gB = (const short*)Bw + (size_t)(n0 + wave * 32 + (lane >> 2)) * K + (lane & 3) * 8;

    auto stage = [&](int bufp, int kt) {
        short* lA = Smem + bufp * 8192 + wave * 1024;
        short* lB = lA + 4096;
        async_copy16(gA + kt,          lA);
        async_copy16(gA + 16 * K + kt, lA + 512);
        async_copy16(gB + kt,          lB);
        async_copy16(gB + 16 * K + kt, lB + 512);
    };

    stage(0, 0);
    __syncthreads();

    int cur = 0;
    for (int kt = 0; kt < K; kt += 32) {
        if (kt + 32 < K) stage(cur ^ 1, kt + 32);

        const short* As = Smem + cur * 8192;
        const short* Bs = As + 4096;
        short8 af[4], bfr[4];
        #pragma unroll
        for (int mt = 0; mt < 4; ++mt)
            af[mt] = *(const short8*)&As[(wm * 64 + mt * 16 + i15) * 32 + q8 * 8];
        #pragma unroll
        for (int nt = 0; nt < 4; ++nt)
            bfr[nt] = *(const short8*)&Bs[(wn * 64 + nt * 16 + i15) * 32 + q8 * 8];
        #pragma unroll
        for (int mt = 0; mt < 4; ++mt)
            #pragma unroll
            for (int nt = 0; nt < 4; ++nt)
                acc[mt][nt] = __builtin_amdgcn_mfma_f32_16x16x32_bf16(af[mt], bfr[nt], acc[mt][nt], 0, 0, 0);

        __syncthreads();
        cur ^= 1;
    }

    #pragma unroll
    for (int nt = 0; nt < 4; ++nt) {
        int n = n0 + wn * 64 + nt * 16 + i15;
        float bv = bias[n];
        #pragma unroll
        for (int mt = 0; mt < 4; ++mt) {
            #pragma unroll
            for (int rg = 0; rg < 4; ++rg) {
                int m = m0 + wm * 64 + mt * 16 + q8 * 4 + rg;
                float v = acc[mt][nt][rg] + bv;
                if (c_bf16) ((bf16*)Cout)[(size_t)m * N + n] = __float2bfloat16(v);
                else        ((float*)Cout)[(size_t)m * N + n] = v;
            }
        }
    }
}

// ---------------------------------------------------------------- MFMA flash attention v11 (r11-verified)
// QBLK=256: 8 waves x 32 q rows (two 16-row groups per wave). Merged branches,
// sigma-permuted K, stride-72 LDS, in-register P, double buffer, one barrier/tile,
// post-barrier prefetch, XCD swizzle. Best-measured of the lockstep family.
__global__ __launch_bounds__(512, 2) void attn11(
    const bf16* __restrict__ Qg, const bf16* __restrict__ Kgg, const bf16* __restrict__ Vtgg,
    const int* __restrict__ cid, const int4* __restrict__ tinfo,
    bf16* __restrict__ Out)
{
    __shared__ short Ks[2][64][72];
    __shared__ short Vs[2][64][72];   // V^T tile: [dim][key]
    __shared__ int cls0_s[NT], cls1_s[NT];
    __shared__ int list_s[2][NT];
    __shared__ int nlist_s[2];

    int tid = threadIdx.x;
    int wave = tid >> 6, lane = tid & 63;
    int i15 = lane & 15, q8 = lane >> 4;
    int workid = ((blockIdx.x & 7) << 5) | (blockIdx.x >> 3);   // 256 blocks, XCD-chunked
    int qt = workid & (NQT2 - 1);
    int h  = (workid >> 3) & (H - 1);
    int b  = workid >> 7;
    int q0 = qt * 256;
    const size_t bh  = (size_t)(b * H + h) * L;
    const size_t bhd = (size_t)(b * H + h) * HD;

    int cq[2];
    #pragma unroll
    for (int g = 0; g < 2; ++g)
        cq[g] = cid[b * L + q0 + g * 128 + wave * 16 + i15];

    // merge the four 64-q tinfo entries for this 256-q block
    int4 qinf;
    {
        int4 e0 = tinfo[b * NT + 4 * qt];
        int4 e1 = tinfo[b * NT + 4 * qt + 1];
        int4 e2 = tinfo[b * NT + 4 * qt + 2];
        int4 e3 = tinfo[b * NT + 4 * qt + 3];
        qinf.x = min(min(e0.x, e1.x), min(e2.x, e3.x));
        qinf.y = max(max(e0.y, e1.y), max(e2.y, e3.y));
        qinf.z = ((e0.z | e1.z | e2.z | e3.z) & 1) | (e0.z & e1.z & e2.z & e3.z & 2);
    }
    int qall = (qinf.z >> 1) & 1;

    if (tid < NT) {
        int4 ki = tinfo[b * NT + tid];
        int kany = ki.z & 1, kall = (ki.z >> 1) & 1;
        bool disjoint = (ki.x > qinf.y) || (ki.y < qinf.x);
        bool mono = qall && kall && (qinf.x == qinf.y) && (ki.x == ki.y) && (qinf.x == ki.x);
        cls0_s[tid] = (!kany || disjoint) ? 0 : (mono ? 2 : 1);
        cls1_s[tid] = (!kany || mono) ? 0 : ((kall && disjoint) ? 2 : 1);
    }
    __syncthreads();
    if (tid < 2) {
        const int* cls = tid ? cls1_s : cls0_s;
        int n = 0;
        for (int t = 0; t < NT; ++t) {
            int c = cls[t];
            if (c) list_s[tid][n++] = (t * 64) | ((c == 2) << 16);
        }
        nlist_s[tid] = n;
    }
    __syncthreads();

    // staging geometry: 512 threads -> row r = tid>>3, 8-short chunk c8 = (tid&7)*8.
    // K stored at sigma-permuted row sr(r); V at plain row r.
    int r = tid >> 3, c8 = (tid & 7) * 8;
    int sr = ((((r >> 2) & 1) | ((r >> 5) << 1)) << 4) | (((r >> 3) & 3) << 2) | (r & 3);

    floatx4 accO[2][2][4];   // [branch][g][t]
    #pragma unroll
    for (int br = 0; br < 2; ++br)
        #pragma unroll
        for (int g = 0; g < 2; ++g)
            #pragma unroll
            for (int t = 0; t < 4; ++t) accO[br][g][t] = (floatx4){0.f, 0.f, 0.f, 0.f};
    float lsum[2][2] = {{0.f, 0.f}, {0.f, 0.f}};

    #pragma unroll
    for (int br = 0; br < 2; ++br) {
        const short* Qb    = (const short*)Qg   + (size_t)br * BHLHD;
        const short* Kbase = (const short*)Kgg  + (size_t)br * BHLHD + (bh + r) * HD + c8;
        const short* Vbase = (const short*)Vtgg + (size_t)br * BHLHD + (bhd + r) * L + c8;
        int n = nlist_s[br];

        // Q fragments for this branch (wave's 2 x 16 q rows)
        short8 qf[2][2];
        #pragma unroll
        for (int g = 0; g < 2; ++g) {
            const short* qp = Qb + (bh + q0 + g * 128 + wave * 16 + i15) * HD + q8 * 8;
            qf[g][0] = *(const short8*)(qp);
            qf[g][1] = *(const short8*)(qp + 32);
        }

        int4 pk, pv;
        int cur = 0;
        if (n > 0) {
            cur = list_s[br][0];
            int kt0 = cur & 0xffff;
            pk = *(const int4*)(Kbase + (size_t)kt0 * HD);
            pv = *(const int4*)(Vbase + kt0);
        }
        __syncthreads();   // prior phase's reads done before overwriting buffers

        for (int i = 0; i < n; ++i) {
            int kt = cur & 0xffff, full = cur >> 16;
            int buf = i & 1;

            *(int4*)&Ks[buf][sr][c8] = pk;
            *(int4*)&Vs[buf][r][c8]  = pv;
            __syncthreads();

            if (i + 1 < n) {
                cur = list_s[br][i + 1];
                int nk = cur & 0xffff;
                pk = *(const int4*)(Kbase + (size_t)nk * HD);
                pv = *(const int4*)(Vbase + nk);
            }

            // S^T = K Q^T (log2 domain); lane's tile-t rows: k = 8*q8 + 4*(t&1) + 32*(t>>1) + rg
            unsigned int dl[2][4], dh[2][4];
            #pragma unroll
            for (int t = 0; t < 4; ++t) {
                short8 b0 = *(const short8*)&Ks[buf][t * 16 + i15][q8 * 8];
                short8 b1 = *(const short8*)&Ks[buf][t * 16 + i15][32 + q8 * 8];

                floatx4 accS[2];
                #pragma unroll
                for (int g = 0; g < 2; ++g) {
                    accS[g] = (floatx4){0.f, 0.f, 0.f, 0.f};
                    accS[g] = __builtin_amdgcn_mfma_f32_16x16x32_bf16(b0, qf[g][0], accS[g], 0, 0, 0);
                    accS[g] = __builtin_amdgcn_mfma_f32_16x16x32_bf16(b1, qf[g][1], accS[g], 0, 0, 0);
                }

                if (!full) {
                    int4 ck4 = *(const int4*)(cid + b * L + kt + (q8 << 3) + ((t & 1) << 2) + ((t >> 1) << 5));
                    int ckr[4] = {ck4.x, ck4.y, ck4.z, ck4.w};
                    #pragma unroll
                    for (int g = 0; g < 2; ++g)
                        #pragma unroll
                        for (int rg = 0; rg < 4; ++rg) {
                            bool kv = (ckr[rg] != INVALID_CID);
                            bool match = (cq[g] == ckr[rg]);
                            bool ok = kv && (br ? !match : match);
                            accS[g][rg] = ok ? accS[g][rg] : -1e30f;
                        }
                }

                #pragma unroll
                for (int g = 0; g < 2; ++g) {
                    float p0 = __builtin_amdgcn_exp2f(accS[g][0]);
                    float p1 = __builtin_amdgcn_exp2f(accS[g][1]);
                    float p2 = __builtin_amdgcn_exp2f(accS[g][2]);
                    float p3 = __builtin_amdgcn_exp2f(accS[g][3]);
                    lsum[br][g] += (p0 + p1) + (p2 + p3);
                    dl[g][t] = (unsigned)(unsigned short)f2bf(p0) | ((unsigned)(unsigned short)f2bf(p1) << 16);
                    dh[g][t] = (unsigned)(unsigned short)f2bf(p2) | ((unsigned)(unsigned short)f2bf(p3) << 16);
                }
            }

            union { uint4v u; short8 s; } pa0[2], pa1[2];
            #pragma unroll
            for (int g = 0; g < 2; ++g) {
                pa0[g].u = (uint4v){dl[g][0], dh[g][0], dl[g][1], dh[g][1]};
                pa1[g].u = (uint4v){dl[g][2], dh[g][2], dl[g][3], dh[g][3]};
            }

            #pragma unroll
            for (int dt = 0; dt < 4; ++dt) {
                short8 vf0 = *(const short8*)&Vs[buf][dt * 16 + i15][q8 * 8];
                short8 vf1 = *(const short8*)&Vs[buf][dt * 16 + i15][32 + q8 * 8];
                #pragma unroll
                for (int g = 0; g < 2; ++g) {
                    accO[br][g][dt] = __builtin_amdgcn_mfma_f32_16x16x32_bf16(pa0[g].s, vf0, accO[br][g][dt], 0, 0, 0);
                    accO[br][g][dt] = __builtin_amdgcn_mfma_f32_16x16x32_bf16(pa1[g].s, vf1, accO[br][g][dt], 0, 0, 0);
                }
            }
        }
    }

    // row-sum reduce per branch/group, then single bf16 output write
    float inv[2][2][4];
    #pragma unroll
    for (int br = 0; br < 2; ++br)
        #pragma unroll
        for (int g = 0; g < 2; ++g) {
            float ls = lsum[br][g];
            ls += __shfl_xor(ls, 16, 64);
            ls += __shfl_xor(ls, 32, 64);
            #pragma unroll
            for (int rg = 0; rg < 4; ++rg) {
                float lv = __shfl(ls, q8 * 4 + rg, 64);
                inv[br][g][rg] = (lv > 0.f) ? 1.f / lv : 0.f;
            }
        }

    #pragma unroll
    for (int g = 0; g < 2; ++g)
        #pragma unroll
        for (int t = 0; t < 4; ++t)
            #pragma unroll
            for (int rg = 0; rg < 4; ++rg) {
                size_t idx = (size_t)(b * L + q0 + g * 128 + wave * 16 + q8 * 4 + rg) * D + h * HD + t * 16 + i15;
                float o = accO[0][g][t][rg] * inv[0][g][rg] + accO[1][g][t][rg] * inv[1][g][rg];
                Out[idx] = __float2bfloat16(o);
            }
}

// ---------------------------------------------------------------- launch
extern "C" void kernel_launch(void* const* d_in, const int* in_sizes, int n_in,
                              void* d_out, int out_size, void* d_ws, size_t ws_size,
                              hipStream_t stream)
{
    const float* x    = (const float*)d_in[0];
    const int*   mlen = (const int*)  d_in[1];
    const float* Wi   = (const float*)d_in[2];
    const float* bi   = (const float*)d_in[3];
    const float* We   = (const float*)d_in[4];
    const float* be   = (const float*)d_in[5];
    const float* Wo   = (const float*)d_in[6];
    const float* bo   = (const float*)d_in[7];

    char* ws = (char*)d_ws;
    size_t off = 0;
    auto alloc = [&](size_t bytes) {
        void* p = ws + off;
        off += (bytes + 255) & ~(size_t)255;
        return p;
    };
    bf16*  x_b   = (bf16*) alloc((size_t)B * L * D * 2);
    bf16*  Wi_b  = (bf16*) alloc((size_t)3 * D * D * 2);   // adjacent to We_b: combined [6144][1024]
    bf16*  We_b  = (bf16*) alloc((size_t)3 * D * D * 2);
    bf16*  Wo_b  = (bf16*) alloc((size_t)D * D * 2);
    bf16*  q_b   = (bf16*) alloc(2 * BHLHD * 2);           // [branch][B,H,L,HD]
    bf16*  k_b   = (bf16*) alloc(2 * BHLHD * 2);
    bf16*  vt_b  = (bf16*) alloc(2 * BHLHD * 2);           // [branch][B,H,HD,L]
    bf16*  sum_b = (bf16*) alloc((size_t)B * L * D * 2);
    float* pos   = (float*)alloc((size_t)B * L * 4);
    int*   cid   = (int*)  alloc((size_t)B * L * 4);
    int4*  tinfo = (int4*) alloc((size_t)B * NT * 16);
    float2* rtab = (float2*)alloc((size_t)B * L * 32 * 8);
    (void)ws_size; (void)n_in; (void)in_sizes; (void)out_size;

    chain_kernel<<<B, 256, 0, stream>>>(mlen, pos, cid, tinfo);

    // fused casts + rope table (rope depends on chain's pos; casts independent)
    prep_kernel<<<11776, 256, 0, stream>>>(x, Wi, We, Wo, x_b, Wi_b, We_b, Wo_b, pos, rtab);

    // fused QKV GEMM + bias + RoPE + scatter (both branches in one pass)
    dim3 gq(6 * D / 128, B * L / 128);
    gemm_qkv<<<gq, 256, 0, stream>>>(x_b, Wi_b, bi, be, rtab, q_b, k_b, vt_b);

    // both attention branches in one dispatch: 8 waves x 256 q rows
    attn11<<<B * H * NQT2, 512, 0, stream>>>(q_b, k_b, vt_b, cid, tinfo, sum_b);

    dim3 go(D / 128, B * L / 128);
    gemm128<<<go, 256, 0, stream>>>(sum_b, Wo_b, bo, d_out, B * L, D, D, 0);
}